// Round 6
// baseline (194.775 us; speedup 1.0000x reference)
//
#include <hip/hip_runtime.h>
#include <stdint.h>
#include <stddef.h>

// ============================================================================
// SumSampler: bit-exact replication of the JAX reference sampler.
// R6 == R5 resubmit (R5 died on GPU-acquisition timeout; no data).
// Within-probe A/B to isolate the sample-phase bottleneck:
//   A (rows 0..255):   2 samples/thread, fully unrolled, pairwise-interleaved
//                      (forced ILP=2), __launch_bounds__(256,4) so the
//                      compiler may use up to 128 VGPR (R4's 36-VGPR
//                      serialization is the suspected ILP killer).
//   B (rows 256..511): rolled candidate loop (#pragma unroll 1, ~6KB code,
//                      I$-friendly) + digit-0 pruning (block-uniform bound
//                      c<=mx0; digit 0 has con==0 by construction).
// Both: v = sp - l2 fold (bit-exact), same weights kernel as R4.
// Locked-in (absmax=0.0 R0/R2/R4): partitionable threefry, Variant-E log,
// f32 outputs [n1_samples | n2d | weights].
// ============================================================================

namespace {

constexpr int B = 512, S = 2048, D = 4, NC = 10;
constexpr int BS = B * S;                       // 1048576
constexpr size_t OUT1_OFF = (size_t)BS * D;     // 4194304
constexpr size_t OUT2_OFF = (size_t)BS * D * 2; // 8388608

// ---------------- constexpr Threefry2x32 (compile-time key derivation) ------
constexpr uint32_t crotl(uint32_t x, int d) { return (x << d) | (x >> (32 - d)); }
struct CU2 { uint32_t a, b; };
constexpr CU2 ctf(uint32_t k0, uint32_t k1, uint32_t c0, uint32_t c1) {
  uint32_t ks2 = k0 ^ k1 ^ 0x1BD11BDAu;
  uint32_t x0 = c0 + k0, x1 = c1 + k1;
  const int rots[8] = {13, 15, 26, 6, 17, 29, 16, 24};
  const uint32_t ks[3] = {k0, k1, ks2};
  for (int blk = 0; blk < 5; ++blk) {
    for (int j = 0; j < 4; ++j) {
      int r = rots[(blk & 1) * 4 + j];
      x0 += x1; x1 = crotl(x1, r); x1 ^= x0;
    }
    x0 += ks[(blk + 1) % 3];
    x1 += ks[(blk + 2) % 3] + (uint32_t)(blk + 1);
  }
  return CU2{x0, x1};
}

struct Keys { uint32_t kx[D]; uint32_t ky[D]; };
constexpr Keys make_keys() {
  Keys K{};
  uint32_t a = 0u, b = 42u;  // jax.random.key(42) -> (0, 42)
  for (int i = 0; i < D; ++i) {
    CU2 sub = ctf(a, b, 0u, 1u);  // split[1] = subkey (foldlike)
    CU2 nk  = ctf(a, b, 0u, 0u);  // split[0] = carried key
    K.kx[i] = sub.a; K.ky[i] = sub.b;
    a = nk.a; b = nk.b;
  }
  return K;
}
constexpr Keys KEYS = make_keys();

// ---------------- device Threefry2x32 ---------------------------------------
__device__ __forceinline__ uint32_t rotl32(uint32_t x, int d) {
  return (x << d) | (x >> (32 - d));   // -> v_alignbit_b32
}
template <uint32_t K0, uint32_t K1>
__device__ __forceinline__ uint32_t tf_xor(uint32_t c1) {
  constexpr uint32_t KS2 = K0 ^ K1 ^ 0x1BD11BDAu;
  uint32_t x0 = K0, x1 = c1 + K1;      // c0 == 0 always
#define TF_RND(r) { x0 += x1; x1 = rotl32(x1, (r)); x1 ^= x0; }
  TF_RND(13) TF_RND(15) TF_RND(26) TF_RND(6)   x0 += K1;  x1 += KS2 + 1u;
  TF_RND(17) TF_RND(29) TF_RND(16) TF_RND(24)  x0 += KS2; x1 += K0 + 2u;
  TF_RND(13) TF_RND(15) TF_RND(26) TF_RND(6)   x0 += K0;  x1 += K1 + 3u;
  TF_RND(17) TF_RND(29) TF_RND(16) TF_RND(24)  x0 += K1;  x1 += KS2 + 4u;
  TF_RND(13) TF_RND(15) TF_RND(26) TF_RND(6)   x0 += KS2; x1 += K0 + 5u;
#undef TF_RND
  return x0 ^ x1;                      // bits1 ^ bits2
}

// ---------------- f32 log: Eigen/Cephes plog, Variant-E (verified R0) -------
__device__ __forceinline__ float xla_logf(float a) {
  uint32_t bits = __float_as_uint(a);
  float e = (float)((int)(bits >> 23) - 126);                    // pfrexp exp
  float m = __uint_as_float((bits & 0x007fffffu) | 0x3f000000u); // [0.5, 1)
  bool mlt = m < 0.707106781186547524f;                          // SQRTHF
  float tmp = mlt ? m : 0.0f;
  float x = __fsub_rn(m, 1.0f);
  e = __fsub_rn(e, mlt ? 1.0f : 0.0f);
  x = __fadd_rn(x, tmp);
  float x2 = __fmul_rn(x, x);
  float x3 = __fmul_rn(x2, x);
  float y  = __fmaf_rn(7.0376836292e-2f,  x, -1.1514610310e-1f);
  float y1 = __fmaf_rn(-1.2420140846e-1f, x,  1.4249322787e-1f);
  float y2 = __fmaf_rn(2.0000714765e-1f,  x, -2.4999993993e-1f);
  y  = __fmaf_rn(y,  x,  1.1676998740e-1f);
  y1 = __fmaf_rn(y1, x, -1.6668057665e-1f);
  y2 = __fmaf_rn(y2, x,  3.3333331174e-1f);
  y  = __fmaf_rn(y, x3, y1);
  y  = __fmaf_rn(y, x3, y2);
  y  = __fmul_rn(y, x3);
  y1 = __fmul_rn(e, -2.12194440e-4f);
  tmp = __fmul_rn(x2, 0.5f);
  y = __fadd_rn(y, y1);
  x = __fsub_rn(x, tmp);
  y2 = __fmul_rn(e, 0.693359375f);
  x = __fadd_rn(x, y);
  x = __fadd_rn(x, y2);
  return x;
}

// l2 such that gumbel g = -l2; caller computes v = sp - l2 (bit-exact fold).
__device__ __forceinline__ float l2_of(uint32_t bits) {
  float f = __fsub_rn(__uint_as_float((bits >> 9) | 0x3f800000u), 1.0f);
  float u = __fadd_rn(f, 1.17549435e-38f);  // == f unless f == 0 -> tiny
  float l1 = xla_logf(u);
  return xla_logf(-l1);
}

// ---------------- variant A: 2 samples/thread, unrolled, forced ILP=2 -------
template <int I>
__device__ __forceinline__ void do_digit2(const float* s_p,
                                          uint32_t n0a, uint32_t n0b, int mxi,
                                          int& conA, int& conB,
                                          int& dgA, int& dgB) {
  // Phase 1: 2x10 independent threefry streams, pairwise interleaved.
  uint32_t ra[NC], rb[NC];
#pragma unroll
  for (int c = 0; c < NC; ++c) {
    ra[c] = tf_xor<KEYS.kx[I], KEYS.ky[I]>(n0a + (uint32_t)c);
    rb[c] = tf_xor<KEYS.kx[I], KEYS.ky[I]>(n0b + (uint32_t)c);
  }
  // Phase 2: 2x10 gumbel (log) chains, pairwise interleaved.
  float la[NC], lb[NC];
#pragma unroll
  for (int c = 0; c < NC; ++c) {
    la[c] = l2_of(ra[c]);
    lb[c] = l2_of(rb[c]);
  }
  // Phase 3: first-max scans.
  float bestA = -__builtin_inff(), bestB = -__builtin_inff();
  int biA = 0, biB = 0;
#pragma unroll
  for (int c = 0; c < NC; ++c) {
    float sp = s_p[I * NC + c];
    float vA = __fsub_rn(sp, la[c]);
    float vB = __fsub_rn(sp, lb[c]);
    bool okA = (conA != 0) || (c <= mxi);
    bool okB = (conB != 0) || (c <= mxi);
    if (okA && vA > bestA) { bestA = vA; biA = c; }
    if (okB && vB > bestB) { bestB = vB; biB = c; }
  }
  dgA = biA; dgB = biB;
  conA |= (biA != mxi); conB |= (biB != mxi);
}

__global__ __launch_bounds__(256, 4) void sample_A(
    const float* __restrict__ logits, const float* __restrict__ counters,
    const int* __restrict__ s_in, float* __restrict__ out,
    int* __restrict__ n1buf, int write_ws)
{
  __shared__ float s_p[D * NC];
  const int t = threadIdx.x;
  const int blk = blockIdx.x;          // 0..1023, rows 0..255
  const int b = blk >> 2;              // 4 blocks (512 samples) per row
  if (t < D * NC)
    s_p[t] = __fsub_rn(logits[b * D * NC + t],
                       __fmul_rn(0.1f, xla_logf(counters[t])));
  __syncthreads();

  const int sidx0 = blk * 512 + 2 * t;       // global sample index (even)
  const int sval = s_in[b];
  const int mx[D] = {sval / 1000, (sval / 100) % 10, (sval / 10) % 10, sval % 10};
  const uint32_t n0a = (uint32_t)sidx0 * NC, n0b = n0a + NC;

  int conA = 0, conB = 0, dgA[D], dgB[D];
  do_digit2<0>(s_p, n0a, n0b, mx[0], conA, conB, dgA[0], dgB[0]);
  do_digit2<1>(s_p, n0a, n0b, mx[1], conA, conB, dgA[1], dgB[1]);
  do_digit2<2>(s_p, n0a, n0b, mx[2], conA, conB, dgA[2], dgB[2]);
  do_digit2<3>(s_p, n0a, n0b, mx[3], conA, conB, dgA[3], dgB[3]);

#pragma unroll
  for (int k = 0; k < 2; ++k) {
    const int* dg = k ? dgB : dgA;
    const int sidx = sidx0 + k;
    const int n1v = dg[0] * 1000 + dg[1] * 100 + dg[2] * 10 + dg[3];
    const int n2 = sval - n1v;
    const size_t o = (size_t)sidx * D;
    *reinterpret_cast<float4*>(out + o) =
        make_float4((float)dg[0], (float)dg[1], (float)dg[2], (float)dg[3]);
    *reinterpret_cast<float4*>(out + OUT1_OFF + o) =
        make_float4((float)(n2 / 1000), (float)((n2 / 100) % 10),
                    (float)((n2 / 10) % 10), (float)(n2 % 10));
    if (write_ws) n1buf[sidx] = n1v;
  }
}

// ---------------- variant B: rolled loop, small code, digit-0 pruning -------
template <int I>
__device__ __forceinline__ void digitB(const float* s_p, uint32_t n0, int mxi,
                                       int& con, int& dg) {
  float best = -__builtin_inff();
  int bi = 0;
  const int lim = (I == 0) ? mxi : (NC - 1);  // digit 0: con==0, prune to mx0
#pragma unroll 1
  for (int c = 0; c <= lim; ++c) {
    uint32_t rbits = tf_xor<KEYS.kx[I], KEYS.ky[I]>(n0 + (uint32_t)c);
    float l2 = l2_of(rbits);
    float v = __fsub_rn(s_p[I * NC + c], l2);
    bool allowed = (I == 0) || (con != 0) || (c <= mxi);
    if (allowed && v > best) { best = v; bi = c; }
  }
  dg = bi;
  con |= (bi != mxi);
}

__global__ __launch_bounds__(256, 4) void sample_B(
    const float* __restrict__ logits, const float* __restrict__ counters,
    const int* __restrict__ s_in, float* __restrict__ out,
    int* __restrict__ n1buf, int write_ws)
{
  __shared__ float s_p[D * NC];
  const int t = threadIdx.x;
  const int blk = blockIdx.x;          // 0..2047, rows 256..511
  const int tid = BS / 2 + blk * 256 + t;
  const int b = tid >> 11;
  if (t < D * NC)
    s_p[t] = __fsub_rn(logits[b * D * NC + t],
                       __fmul_rn(0.1f, xla_logf(counters[t])));
  __syncthreads();

  const int sval = s_in[b];
  const int mx[D] = {sval / 1000, (sval / 100) % 10, (sval / 10) % 10, sval % 10};
  const uint32_t n0 = (uint32_t)tid * NC;

  int con = 0, dg[D];
  digitB<0>(s_p, n0, mx[0], con, dg[0]);
  digitB<1>(s_p, n0, mx[1], con, dg[1]);
  digitB<2>(s_p, n0, mx[2], con, dg[2]);
  digitB<3>(s_p, n0, mx[3], con, dg[3]);

  const int n1v = dg[0] * 1000 + dg[1] * 100 + dg[2] * 10 + dg[3];
  const int n2 = sval - n1v;
  const size_t o = (size_t)tid * D;
  *reinterpret_cast<float4*>(out + o) =
      make_float4((float)dg[0], (float)dg[1], (float)dg[2], (float)dg[3]);
  *reinterpret_cast<float4*>(out + OUT1_OFF + o) =
      make_float4((float)(n2 / 1000), (float)((n2 / 100) % 10),
                  (float)((n2 / 10) % 10), (float)(n2 % 10));
  if (write_ws) n1buf[tid] = n1v;
}

// ---------------- per-row multiplicity (weights) ----------------------------
template <bool FROM_WS>
__global__ __launch_bounds__(256) void weights_kernel(
    const int* __restrict__ n1buf, float* __restrict__ out) {
  __shared__ int hist[10000];           // 40 KB
  const int t = threadIdx.x;
  const int b = blockIdx.x;
  for (int i = t; i < 10000; i += 256) hist[i] = 0;
  __syncthreads();
  int vals[8];
#pragma unroll
  for (int k = 0; k < 8; ++k) {
    const int sidx = t + k * 256;
    int v;
    if (FROM_WS) {
      v = n1buf[b * S + sidx];
    } else {
      const float* p = out + ((size_t)(b * S + sidx)) * D;
      v = 1000 * (int)p[0] + 100 * (int)p[1] + 10 * (int)p[2] + (int)p[3];
    }
    vals[k] = v;
    atomicAdd(&hist[v], 1);
  }
  __syncthreads();
#pragma unroll
  for (int k = 0; k < 8; ++k) {
    const int sidx = t + k * 256;
    out[OUT2_OFF + (size_t)b * S + sidx] = (float)hist[vals[k]];
  }
}

}  // namespace

extern "C" void kernel_launch(void* const* d_in, const int* in_sizes, int n_in,
                              void* d_out, int out_size, void* d_ws, size_t ws_size,
                              hipStream_t stream) {
  const float* logits   = (const float*)d_in[0];  // [512,4,10]
  const float* counters = (const float*)d_in[1];  // [4,10]
  const int*   s_in     = (const int*)d_in[2];    // [512]
  float* out = (float*)d_out;
  int*   n1buf = (int*)d_ws;
  const int use_ws = (d_ws != nullptr && ws_size >= (size_t)BS * sizeof(int)) ? 1 : 0;

  sample_A<<<1024, 256, 0, stream>>>(logits, counters, s_in, out, n1buf, use_ws);
  sample_B<<<2048, 256, 0, stream>>>(logits, counters, s_in, out, n1buf, use_ws);
  if (use_ws) weights_kernel<true><<<B, 256, 0, stream>>>(n1buf, out);
  else        weights_kernel<false><<<B, 256, 0, stream>>>(nullptr, out);
}

// Round 8
// 190.249 us; speedup vs baseline: 1.0238x; 1.0238x over previous
//
#include <hip/hip_runtime.h>
#include <stdint.h>
#include <stddef.h>

// ============================================================================
// SumSampler: bit-exact replication of the JAX reference sampler.
// R8 = R7 with the counter-index bug fixed: every digit uses index base
//      n0 = tid*10 (distinct per-digit KEYS make the streams distinct).
//      R7's "n0 + I*NC" shifted digits 1..3 onto neighbors' counters.
// Also learned from R7's failure trace: the harness threshold is a scalar
// (22.88) broadcast to all outputs -> only output 2 (weights) can ever
// discriminate correctness. Digits passing proves nothing.
// Structure: sampler = R4 + digit-0 uniform pruning, split into 4
// quarter-dispatches so the weights kernel (suspected ~50us, never yet
// profiled) must appear in rocprof top-5. Weights kernel byte-identical
// to R4 for interpretable counters.
// Locked-in (absmax=0.0 R0/R2/R4/R6): partitionable threefry, Variant-E log,
// v = sp - l2 fold, f32 outputs [n1_samples | n2d | weights].
// ============================================================================

namespace {

constexpr int B = 512, S = 2048, D = 4, NC = 10;
constexpr int BS = B * S;                       // 1048576
constexpr size_t OUT1_OFF = (size_t)BS * D;     // 4194304
constexpr size_t OUT2_OFF = (size_t)BS * D * 2; // 8388608
constexpr int QBLOCKS = 1024;                   // blocks per quarter-dispatch

// ---------------- constexpr Threefry2x32 (compile-time key derivation) ------
constexpr uint32_t crotl(uint32_t x, int d) { return (x << d) | (x >> (32 - d)); }
struct CU2 { uint32_t a, b; };
constexpr CU2 ctf(uint32_t k0, uint32_t k1, uint32_t c0, uint32_t c1) {
  uint32_t ks2 = k0 ^ k1 ^ 0x1BD11BDAu;
  uint32_t x0 = c0 + k0, x1 = c1 + k1;
  const int rots[8] = {13, 15, 26, 6, 17, 29, 16, 24};
  const uint32_t ks[3] = {k0, k1, ks2};
  for (int blk = 0; blk < 5; ++blk) {
    for (int j = 0; j < 4; ++j) {
      int r = rots[(blk & 1) * 4 + j];
      x0 += x1; x1 = crotl(x1, r); x1 ^= x0;
    }
    x0 += ks[(blk + 1) % 3];
    x1 += ks[(blk + 2) % 3] + (uint32_t)(blk + 1);
  }
  return CU2{x0, x1};
}

struct Keys { uint32_t kx[D]; uint32_t ky[D]; };
constexpr Keys make_keys() {
  Keys K{};
  uint32_t a = 0u, b = 42u;  // jax.random.key(42) -> (0, 42)
  for (int i = 0; i < D; ++i) {
    CU2 sub = ctf(a, b, 0u, 1u);  // split[1] = subkey (foldlike)
    CU2 nk  = ctf(a, b, 0u, 0u);  // split[0] = carried key
    K.kx[i] = sub.a; K.ky[i] = sub.b;
    a = nk.a; b = nk.b;
  }
  return K;
}
constexpr Keys KEYS = make_keys();

// ---------------- device Threefry2x32 ---------------------------------------
__device__ __forceinline__ uint32_t rotl32(uint32_t x, int d) {
  return (x << d) | (x >> (32 - d));   // -> v_alignbit_b32
}
template <uint32_t K0, uint32_t K1>
__device__ __forceinline__ uint32_t tf_xor(uint32_t c1) {
  constexpr uint32_t KS2 = K0 ^ K1 ^ 0x1BD11BDAu;
  uint32_t x0 = K0, x1 = c1 + K1;      // c0 == 0 always
#define TF_RND(r) { x0 += x1; x1 = rotl32(x1, (r)); x1 ^= x0; }
  TF_RND(13) TF_RND(15) TF_RND(26) TF_RND(6)   x0 += K1;  x1 += KS2 + 1u;
  TF_RND(17) TF_RND(29) TF_RND(16) TF_RND(24)  x0 += KS2; x1 += K0 + 2u;
  TF_RND(13) TF_RND(15) TF_RND(26) TF_RND(6)   x0 += K0;  x1 += K1 + 3u;
  TF_RND(17) TF_RND(29) TF_RND(16) TF_RND(24)  x0 += K1;  x1 += KS2 + 4u;
  TF_RND(13) TF_RND(15) TF_RND(26) TF_RND(6)   x0 += KS2; x1 += K0 + 5u;
#undef TF_RND
  return x0 ^ x1;                      // bits1 ^ bits2
}

// ---------------- f32 log: Eigen/Cephes plog, Variant-E (verified R0) -------
__device__ __forceinline__ float xla_logf(float a) {
  uint32_t bits = __float_as_uint(a);
  float e = (float)((int)(bits >> 23) - 126);                    // pfrexp exp
  float m = __uint_as_float((bits & 0x007fffffu) | 0x3f000000u); // [0.5, 1)
  bool mlt = m < 0.707106781186547524f;                          // SQRTHF
  float tmp = mlt ? m : 0.0f;
  float x = __fsub_rn(m, 1.0f);
  e = __fsub_rn(e, mlt ? 1.0f : 0.0f);
  x = __fadd_rn(x, tmp);
  float x2 = __fmul_rn(x, x);
  float x3 = __fmul_rn(x2, x);
  float y  = __fmaf_rn(7.0376836292e-2f,  x, -1.1514610310e-1f);
  float y1 = __fmaf_rn(-1.2420140846e-1f, x,  1.4249322787e-1f);
  float y2 = __fmaf_rn(2.0000714765e-1f,  x, -2.4999993993e-1f);
  y  = __fmaf_rn(y,  x,  1.1676998740e-1f);
  y1 = __fmaf_rn(y1, x, -1.6668057665e-1f);
  y2 = __fmaf_rn(y2, x,  3.3333331174e-1f);
  y  = __fmaf_rn(y, x3, y1);
  y  = __fmaf_rn(y, x3, y2);
  y  = __fmul_rn(y, x3);
  y1 = __fmul_rn(e, -2.12194440e-4f);
  tmp = __fmul_rn(x2, 0.5f);
  y = __fadd_rn(y, y1);
  x = __fsub_rn(x, tmp);
  y2 = __fmul_rn(e, 0.693359375f);
  x = __fadd_rn(x, y);
  x = __fadd_rn(x, y2);
  return x;
}

// l2 such that gumbel g = -l2; caller computes v = sp - l2 (bit-exact fold).
__device__ __forceinline__ float l2_of(uint32_t bits) {
  float f = __fsub_rn(__uint_as_float((bits >> 9) | 0x3f800000u), 1.0f);
  float u = __fadd_rn(f, 1.17549435e-38f);  // == f unless f == 0 -> tiny
  float l1 = xla_logf(u);
  return xla_logf(-l1);
}

__device__ __forceinline__ float sgpr_f(float x) {
  return __uint_as_float(__builtin_amdgcn_readfirstlane(__float_as_uint(x)));
}

// ---------------- per-digit sampler, digits 1..3 (R4 structure) -------------
// Index base is n0 = tid*NC for EVERY digit (distinct keys, same counters).
template <int I>
__device__ __forceinline__ void do_digit(const float* s_p, uint32_t n0,
                                         const int* mx, int& con, int* dg) {
  // Phase 1: 10 independent threefry streams -> reg array (ILP).
  uint32_t rb[NC];
#pragma unroll
  for (int c = 0; c < NC; ++c)
    rb[c] = tf_xor<KEYS.kx[I], KEYS.ky[I]>(n0 + (uint32_t)c);
  // Phase 2: row-uniform p into SGPRs (short live range, per digit).
  float sp[NC];
#pragma unroll
  for (int c = 0; c < NC; ++c) sp[c] = sgpr_f(s_p[I * NC + c]);
  // Phase 3: 10 independent gumbel chains + first-max scan.
  const int mxi = mx[I];
  float best = -__builtin_inff();
  int bi = 0;
#pragma unroll
  for (int c = 0; c < NC; ++c) {
    float l2 = l2_of(rb[c]);
    float v = __fsub_rn(sp[c], l2);
    bool allowed = (con != 0) || (c <= mxi);
    if (allowed && v > best) { best = v; bi = c; }   // first max wins
  }
  dg[I] = bi;
  con |= (bi != mxi);
}

// ---------------- digit 0: uniform-pruned (con==0, minim==0 always) ---------
__device__ __forceinline__ void do_digit0(const float* s_p, uint32_t n0,
                                          int mx0, int& con, int* dg) {
  const int m0 = __builtin_amdgcn_readfirstlane(mx0);  // block-uniform bound
  float sp[NC];
#pragma unroll
  for (int c = 0; c < NC; ++c) sp[c] = sgpr_f(s_p[c]);
  // c = 0 always valid (allowed: 0 <= mx0 always)
  float best = __fsub_rn(sp[0], l2_of(tf_xor<KEYS.kx[0], KEYS.ky[0]>(n0)));
  int bi = 0;
#pragma unroll
  for (int c = 1; c < NC; ++c) {
    if (m0 >= c) {                     // scalar branch: skip dead candidates
      float l2 = l2_of(tf_xor<KEYS.kx[0], KEYS.ky[0]>(n0 + (uint32_t)c));
      float v = __fsub_rn(sp[c], l2);
      if (v > best) { best = v; bi = c; }
    }
  }
  dg[0] = bi;
  con |= (bi != mx0);
}

// ---------------- sampling kernel (quarter-batch per dispatch) --------------
__global__ __launch_bounds__(256) void sample_kernel(
    const float* __restrict__ logits,   // [B, D, NC]
    const float* __restrict__ counters, // [D, NC]
    const int*   __restrict__ s_in,     // [B]
    float* __restrict__ out,            // concat(n1_samples, n2d, weights)
    int*   __restrict__ n1buf,          // [BS] scratch (may be null)
    int    write_ws, int qi)            // quarter index 0..3
{
  __shared__ float s_p[D * NC];         // logit - 0.1*log(counter), this row
  const int t = threadIdx.x;
  const int gblk = qi * QBLOCKS + blockIdx.x;   // 0..4095
  const int b = gblk >> 3;              // 8 blocks per row
  if (t < D * NC) {
    s_p[t] = __fsub_rn(logits[b * D * NC + t],
                       __fmul_rn(0.1f, xla_logf(counters[t])));
  }
  __syncthreads();

  const int tid = gblk * 256 + t;       // == b*S + sidx
  const int sval = s_in[b];
  const int mx[D] = {sval / 1000, (sval / 100) % 10, (sval / 10) % 10, sval % 10};

  const uint32_t n0 = (uint32_t)tid * (uint32_t)NC;  // SAME base for all digits
  int con = 0;
  int dg[D];
  do_digit0(s_p, n0, mx[0], con, dg);
  do_digit<1>(s_p, n0, mx, con, dg);
  do_digit<2>(s_p, n0, mx, con, dg);
  do_digit<3>(s_p, n0, mx, con, dg);

  const int n1v = dg[0] * 1000 + dg[1] * 100 + dg[2] * 10 + dg[3];
  const int n2 = sval - n1v;            // in [0, 10^D)
  const int q0 = n2 / 1000, q1 = (n2 / 100) % 10, q2 = (n2 / 10) % 10, q3 = n2 % 10;

  const size_t o = (size_t)tid * D;
  *reinterpret_cast<float4*>(out + o) =
      make_float4((float)dg[0], (float)dg[1], (float)dg[2], (float)dg[3]);
  *reinterpret_cast<float4*>(out + OUT1_OFF + o) =
      make_float4((float)q0, (float)q1, (float)q2, (float)q3);
  if (write_ws) n1buf[tid] = n1v;
}

// ---------------- per-row multiplicity (weights) — BYTE-IDENTICAL to R4 -----
template <bool FROM_WS>
__global__ __launch_bounds__(256) void weights_kernel(
    const int* __restrict__ n1buf, float* __restrict__ out) {
  __shared__ int hist[10000];           // 40 KB
  const int t = threadIdx.x;
  const int b = blockIdx.x;
  for (int i = t; i < 10000; i += 256) hist[i] = 0;
  __syncthreads();
  int vals[8];
#pragma unroll
  for (int k = 0; k < 8; ++k) {
    const int sidx = t + k * 256;
    int v;
    if (FROM_WS) {
      v = n1buf[b * S + sidx];
    } else {
      const float* p = out + ((size_t)(b * S + sidx)) * D;
      v = 1000 * (int)p[0] + 100 * (int)p[1] + 10 * (int)p[2] + (int)p[3];
    }
    vals[k] = v;
    atomicAdd(&hist[v], 1);
  }
  __syncthreads();
#pragma unroll
  for (int k = 0; k < 8; ++k) {
    const int sidx = t + k * 256;
    out[OUT2_OFF + (size_t)b * S + sidx] = (float)hist[vals[k]];
  }
}

}  // namespace

extern "C" void kernel_launch(void* const* d_in, const int* in_sizes, int n_in,
                              void* d_out, int out_size, void* d_ws, size_t ws_size,
                              hipStream_t stream) {
  const float* logits   = (const float*)d_in[0];  // [512,4,10]
  const float* counters = (const float*)d_in[1];  // [4,10]
  const int*   s_in     = (const int*)d_in[2];    // [512]
  float* out = (float*)d_out;
  int*   n1buf = (int*)d_ws;
  const int use_ws = (d_ws != nullptr && ws_size >= (size_t)BS * sizeof(int)) ? 1 : 0;

  for (int qi = 0; qi < 4; ++qi)
    sample_kernel<<<QBLOCKS, 256, 0, stream>>>(logits, counters, s_in, out,
                                               n1buf, use_ws, qi);
  if (use_ws) weights_kernel<true><<<B, 256, 0, stream>>>(n1buf, out);
  else        weights_kernel<false><<<B, 256, 0, stream>>>(nullptr, out);
}